// Round 15
// baseline (852.326 us; speedup 1.0000x reference)
//
#include <hip/hip_runtime.h>
#include <hip/hip_fp8.h>

typedef unsigned short u16;
typedef unsigned char u8;
typedef __attribute__((ext_vector_type(8))) __bf16 bfrag;
typedef long long f8frag;
typedef __attribute__((ext_vector_type(4))) float f32x4;

static __device__ __forceinline__ f32x4 MFMA(bfrag a, bfrag b, f32x4 c) {
  return __builtin_amdgcn_mfma_f32_16x16x32_bf16(a, b, c, 0, 0, 0);
}
static __device__ __forceinline__ f32x4 MFMA8(f8frag a, f8frag b, f32x4 c) {
  return __builtin_amdgcn_mfma_f32_16x16x32_fp8_fp8(a, b, c, 0, 0, 0);
}

// float -> bf16 (RNE)
static __device__ __forceinline__ u16 f2b(float f) {
  union { float f; unsigned u; } v; v.f = f;
  unsigned r = (v.u + 0x7fffu + ((v.u >> 16) & 1u)) >> 16;
  return (u16)r;
}
// float -> fp8 e4m3 via HW cvt (gfx950: OCP e4m3fn)
static __device__ __forceinline__ u8 f2e4m3(float f) {
  return (u8)(__builtin_amdgcn_cvt_pk_fp8_f32(f, f, 0, false) & 0xff);
}
static __device__ __forceinline__ unsigned pk4_e4m3(float a, float b, float c, float d) {
  int p = __builtin_amdgcn_cvt_pk_fp8_f32(a, b, 0, false);
  p = __builtin_amdgcn_cvt_pk_fp8_f32(c, d, p, true);
  return (unsigned)p;
}
// 1.f/x without fast-math emits the IEEE div sequence (~8 ops); v_rcp is 1.
static __device__ __forceinline__ float rcp(float x) { return __builtin_amdgcn_rcpf(x); }
static __device__ __forceinline__ float ssig(float x) {
  float E = __expf(x);
  return E * rcp(1.f + E);
}
// Shared-denominator LSTM cell (harness-verified R6/R9/R10/R12):
// cn = [c*Ef*QR + Ei*P*(Eg-1)] / (P*QR), hn = Eo(Ec-1)/[(1+Eo)(Ec+1)].
static __device__ __forceinline__ float2 lstm2(float gi, float gf, float gg,
                                               float go, float c) {
  float Ei = __expf(gi), Ef = __expf(gf), Eg = __expf(2.f * gg), Eo = __expf(go);
  float P = 1.f + Ef, Q = 1.f + Ei, R = 1.f + Eg;
  float QR = Q * R;
  float num = c * Ef * QR + Ei * P * (Eg - 1.f);
  float cn = num * rcp(P * QR);
  float Ec = __expf(2.f * cn);
  float hn = Eo * (Ec - 1.f) * rcp((1.f + Eo) * (Ec + 1.f));
  return make_float2(hn, cn);
}

// barrier that waits only on LDS traffic (no vmcnt store-ack drain)
#define LDS_BARRIER() asm volatile("s_waitcnt lgkmcnt(0)\ns_barrier" ::: "memory")
#define PIN_A8(A) asm volatile("" : "+a"(A[0]), "+a"(A[1]), "+a"(A[2]), "+a"(A[3]), \
                                    "+a"(A[4]), "+a"(A[5]), "+a"(A[6]), "+a"(A[7]))
#define PIN_V8(A) asm volatile("" : "+v"(A[0]), "+v"(A[1]), "+v"(A[2]), "+v"(A[3]), \
                                    "+v"(A[4]), "+v"(A[5]), "+v"(A[6]), "+v"(A[7]))

// ---------------------------------------------------------------------------
// prep (R10/R12 layouts, harness-verified; case 14 zeroes the flags)
// ---------------------------------------------------------------------------
struct PrepArgs {
  const float *x, *W1, *W2, *W3, *Wh1, *Wc1, *Wx1, *Wh2, *Wc2, *Wx2;
  const float *rWih, *rWhh, *rbih, *rbhh, *pWih, *pWhh, *pbih, *pbhh;
  u16 *Xbf, *W1b, *W2b, *W3b, *Wh1b, *Wc1b, *Wx1b, *Wh2b, *Wc2b, *Wx2b;
  u16 *WcatR;
  u8 *WsS, *pWsS, *pWhhS;
  float *rbR, *pbR;
  unsigned *flags;
};

static __device__ __forceinline__ void emit_stream(u16* dst, const float* src,
                                                   int i, int K, int ktbits) {
  int j = i & 7, lane = (i >> 3) & 63;
  int kt = (i >> 9) & ((1 << ktbits) - 1);
  int nt = (i >> (9 + ktbits)) & 3;
  int ct = i >> (11 + ktbits);
  int srow = ct * 64 + nt * 16 + (lane & 15);
  int scol = kt * 32 + ((lane >> 4) & 3) * 8 + j;
  dst[i] = f2b(src[srow * K + scol]);
}

__global__ __launch_bounds__(256) void prep(PrepArgs p) {
  const int tid0 = blockIdx.x * 256 + threadIdx.x;
  const int stride = gridDim.x * 256;
  switch (blockIdx.y) {
    case 0: for (int i = tid0; i < 131072; i += stride) p.Xbf[i] = f2b(p.x[i]); break;
    case 1: for (int i = tid0; i < 65536;  i += stride) emit_stream(p.W1b, p.W1, i, 128, 2); break;
    case 2: for (int i = tid0; i < 262144; i += stride) emit_stream(p.W2b, p.W2, i, 512, 4); break;
    case 3: for (int i = tid0; i < 262144; i += stride) emit_stream(p.W3b, p.W3, i, 512, 4); break;
    case 4: for (int i = tid0; i < 262144; i += stride) emit_stream(p.Wh1b, p.Wh1, i, 512, 4); break;
    case 5: for (int i = tid0; i < 262144; i += stride) emit_stream(p.Wc1b, p.Wc1, i, 512, 4); break;
    case 6: for (int i = tid0; i < 262144; i += stride) emit_stream(p.Wx1b, p.Wx1, i, 512, 4); break;
    case 7: for (int i = tid0; i < 131072; i += stride) emit_stream(p.Wh2b, p.Wh2, i, 512, 4); break;
    case 8: for (int i = tid0; i < 131072; i += stride) emit_stream(p.Wc2b, p.Wc2, i, 512, 4); break;
    case 9: for (int i = tid0; i < 131072; i += stride) emit_stream(p.Wx2b, p.Wx2, i, 512, 4); break;
    case 10: // step-0 concat weights, gate-retiled + stream (K=512)
      for (int i = tid0; i < 524288; i += stride) {
        int j = i & 7, lane = (i >> 3) & 63, kt = (i >> 9) & 15;
        int gate = (i >> 13) & 3, w16 = i >> 15;
        int srow = gate * 256 + w16 * 16 + (lane & 15);
        int k = kt * 32 + ((lane >> 4) & 3) * 8 + j;
        float v = (k < 256) ? p.rWih[srow * 256 + k] : p.rWhh[srow * 256 + (k - 256)];
        p.WcatR[i] = f2b(v);
      }
      break;
    case 11:
      for (int i = tid0; i < 1024; i += stride) {
        int srow = (((i >> 4) & 3) << 8) + ((i >> 6) << 4) + (i & 15);
        p.rbR[i] = p.rbih[srow] + p.rbhh[srow];
      }
      break;
    case 12: // pred x-weights fp8, swizzled-contiguous
      for (int i = tid0; i < 32768; i += stride) {
        int j = i & 7, lane = (i >> 3) & 63, kt = (i >> 9) & 7, w = i >> 12;
        int n = w * 16 + (lane & 15);
        int srow = ((n & 3) << 5) + (n >> 2);
        int k = kt * 32 + ((lane >> 4) & 3) * 8 + j;
        p.pWsS[i] = f2e4m3(p.pWih[srow * 256 + k]);
      }
      break;
    case 13: // pred h-weights fp8, swizzled-contiguous
      for (int i = tid0; i < 4096; i += stride) {
        int j = i & 7, lane = (i >> 3) & 63, w = i >> 9;
        int n = w * 16 + (lane & 15);
        int srow = ((n & 3) << 5) + (n >> 2);
        int k = ((lane >> 4) & 3) * 8 + j;
        p.pWhhS[i] = f2e4m3(p.pWhh[srow * 32 + k]);
      }
      break;
    case 14:
      for (int i = tid0; i < 128; i += stride) {
        int srow = ((i & 3) << 5) + (i >> 2);
        p.pbR[i] = p.pbih[srow] + p.pbhh[srow];
      }
      for (int i = tid0; i < 64; i += stride)
        __hip_atomic_store(p.flags + i, 0u, __ATOMIC_RELAXED, __HIP_MEMORY_SCOPE_AGENT);
      break;
    case 15: // decode combined weights fp8, swizzled-contiguous stream layout
      for (int i = tid0; i < 262144; i += stride) {
        int j = i & 7, lane = (i >> 3) & 63, kt = (i >> 9) & 7;
        int gate = (i >> 12) & 3, g16 = i >> 14;
        int srow = gate * 256 + g16 * 16 + (lane & 15);
        int k = kt * 32 + ((lane >> 4) & 3) * 8 + j;
        p.WsS[i] = f2e4m3(p.rWih[srow * 256 + k] + p.rWhh[srow * 256 + k]);
      }
      break;
  }
}

// ---------------------------------------------------------------------------
// gemm_act: Y[1024,N] = act(X[1024,K] @ W^T + bias), stream-layout weights.
// ---------------------------------------------------------------------------
__global__ __launch_bounds__(256) void gemm_act(
    const u16* __restrict__ X, const u16* __restrict__ W,
    const float* __restrict__ bias,
    u16* __restrict__ Yb, float* __restrict__ Yf,
    int K, int ldo, int coloff, int leaky) {
  const int rt = blockIdx.x, ct = blockIdx.y;
  const int lane = threadIdx.x & 63, wave = threadIdx.x >> 6;
  const int m15 = lane & 15, q = lane >> 4, kq = q * 8;
  const int KT = K >> 5;
  const int row = rt * 64 + wave * 16 + m15;
  f32x4 acc[4] = {};
  const u16* xp = X + (size_t)row * K + kq;
  const u16* wst = W + lane * 8;
  for (int kt = 0; kt < KT; kt++) {
    bfrag a = *(const bfrag*)(xp + kt * 32);
#pragma unroll
    for (int nt = 0; nt < 4; nt++) {
      const u16* wp = wst + (size_t)((ct * 4 + nt) * KT + kt) * 512;
      acc[nt] = MFMA(a, *(const bfrag*)wp, acc[nt]);
    }
  }
#pragma unroll
  for (int nt = 0; nt < 4; nt++) {
    int col = ct * 64 + nt * 16 + m15;
    float bv = bias[col];
#pragma unroll
    for (int r = 0; r < 4; r++) {
      int orow = rt * 64 + wave * 16 + q * 4 + r;
      float v = acc[nt][r] + bv;
      if (leaky) v = v >= 0.f ? v : 0.2f * v;
      if (Yb) Yb[(size_t)orow * ldo + coloff + col] = f2b(v);
      else    Yf[(size_t)orow * ldo + coloff + col] = v;
    }
  }
}

// three independent gemms in one dispatch (blockIdx.z selects)
struct G3 {
  const u16 *X, *W;
  const float* bias;
  u16* Yb;
  float* Yf;
  int K, ldo, coloff, leaky;
};
__global__ __launch_bounds__(256) void gemm_act3(G3 ga, G3 gb, G3 gc) {
  G3 g = (blockIdx.z == 0) ? ga : (blockIdx.z == 1) ? gb : gc;
  const int rt = blockIdx.x, ct = blockIdx.y;
  const int lane = threadIdx.x & 63, wave = threadIdx.x >> 6;
  const int m15 = lane & 15, q = lane >> 4, kq = q * 8;
  const int KT = g.K >> 5;
  const int row = rt * 64 + wave * 16 + m15;
  f32x4 acc[4] = {};
  const u16* xp = g.X + (size_t)row * g.K + kq;
  const u16* wst = g.W + lane * 8;
  for (int kt = 0; kt < KT; kt++) {
    bfrag a = *(const bfrag*)(xp + kt * 32);
#pragma unroll
    for (int nt = 0; nt < 4; nt++) {
      const u16* wp = wst + (size_t)((ct * 4 + nt) * KT + kt) * 512;
      acc[nt] = MFMA(a, *(const bfrag*)wp, acc[nt]);
    }
  }
#pragma unroll
  for (int nt = 0; nt < 4; nt++) {
    int col = ct * 64 + nt * 16 + m15;
    float bv = g.bias[col];
#pragma unroll
    for (int r = 0; r < 4; r++) {
      int orow = rt * 64 + wave * 16 + q * 4 + r;
      float v = acc[nt][r] + bv;
      if (g.leaky) v = v >= 0.f ? v : 0.2f * v;
      if (g.Yb) g.Yb[(size_t)orow * g.ldo + g.coloff + col] = f2b(v);
      else      g.Yf[(size_t)orow * g.ldo + g.coloff + col] = v;
    }
  }
}

// ---------------------------------------------------------------------------
// decode_pred v19: R12 (best verified, 459.2us) with ALL FOUR gate weight
// sets AGPR-pinned (48+16 = 64 AGPRs full; accs in arch VGPRs — the exact
// register shape that compiled clean in R4/R5). Removes 8 ds_read_b64 per
// step and the 64KB WoL staging from the producer's critical path.
// Everything else byte-identical to R12 (atomic hG stores, 4-step publish,
// R12 consumer).
// ---------------------------------------------------------------------------
__global__ __attribute__((amdgpu_flat_work_group_size(1024, 1024), amdgpu_waves_per_eu(4, 4)))
void decode_pred(
    const u8* __restrict__ WsS,     // [262144] fp8 decode weights (stream)
    const u16* __restrict__ WcatR,  // [1024][512] bf16 step-0 weights (stream)
    const float* __restrict__ rb,   // rbR [1024]
    const float* __restrict__ CB,   // [1024][256] c0 (fp32, from c-head gemm)
    const u16* __restrict__ X0H,    // [1024][512] bf16: cols 0-255 x0, 256-511 h
    const u8* __restrict__ pWsS,    // [32768] fp8 pred x-weights (stream)
    const u8* __restrict__ pWhhS,   // [4096] fp8 pred h-weights (stream)
    const float* __restrict__ pb,   // pbR [128]
    float* __restrict__ out,        // [1024][128][32]
    u8* __restrict__ hG,            // [64][128][4096] fp8 h stream
    unsigned* __restrict__ flags) { // [64] chunk progress (4 steps/chunk)
  __shared__ __align__(16) u8 hbufS[2][4096];   // producer h ping-pong
  __shared__ __align__(16) u8 stageL[16384];    // consumer 4-step stage
  __shared__ __align__(16) u8 hp8[2][16][40];   // consumer pred hidden
  __shared__ float ysC[4][16][36];              // consumer y chunk
  const int tid = threadIdx.x;
  const int w = tid >> 6, lane = tid & 63;
  const int m15 = lane & 15, q = lane >> 4;

  if (blockIdx.x < 64) {
    // ================= producer =================
    const int b = blockIdx.x;
    const int rowg = b * 16;
    const float* rbp = rb + w * 64 + q * 4;
    f32x4 rbv0 = *(const f32x4*)(rbp +  0);
    f32x4 rbv1 = *(const f32x4*)(rbp + 16);
    f32x4 rbv2 = *(const f32x4*)(rbp + 32);
    f32x4 rbv3 = *(const f32x4*)(rbp + 48);
    asm volatile("" : "+v"(rbv0), "+v"(rbv1), "+v"(rbv2), "+v"(rbv3));
    f32x4 cst = *(const f32x4*)(CB + (size_t)(rowg + m15) * 256 + w * 16 + q * 4);
    const int wroff = (w >> 1) * 512 + ((w & 1) * 2 + (q >> 1)) * 128 + m15 * 8 + (q & 1) * 4;
    u8* hGs = hG + (size_t)b * 524288 + wroff;

    // ---- prologue: step 0, K=512 over [x0 | h] with stream WcatR ----
    {
      f32x4 ai = rbv0, af_ = rbv1, ag = rbv2, ao = rbv3;
      const u16* xrow = X0H + (size_t)(rowg + m15) * 512 + q * 8;
      const u16* wcw = WcatR + (size_t)w * 32768 + lane * 8;
#pragma unroll
      for (int kt = 0; kt < 16; kt++) {
        bfrag a = *(const bfrag*)(xrow + kt * 32);
        ai  = MFMA(*(const bfrag*)(wcw + kt * 512), a, ai);
        af_ = MFMA(*(const bfrag*)(wcw + 8192 + kt * 512), a, af_);
        ag  = MFMA(*(const bfrag*)(wcw + 16384 + kt * 512), a, ag);
        ao  = MFMA(*(const bfrag*)(wcw + 24576 + kt * 512), a, ao);
      }
      float hn[4];
#pragma unroll
      for (int r = 0; r < 4; r++) {
        float2 hc2 = lstm2(ai[r], af_[r], ag[r], ao[r], cst[r]);
        hn[r] = hc2.x;
        cst[r] = hc2.y;
      }
      unsigned hv = pk4_e4m3(hn[0], hn[1], hn[2], hn[3]);
      *(unsigned*)(&hbufS[0][wroff]) = hv;
      __hip_atomic_store((unsigned*)hGs, hv, __ATOMIC_RELAXED, __HIP_MEMORY_SCOPE_AGENT);
    }
    // all 4 gate weight sets resident: 32 frags = 64 AGPRs (accs in arch)
    const u8* wsb = WsS + (size_t)w * 16384 + lane * 8;
    f8frag Wv0[8], Wv1[8], Wv2[8], Wv3[8];
#pragma unroll
    for (int kt = 0; kt < 8; kt++) {
      Wv0[kt] = *(const f8frag*)(wsb + kt * 512);
      Wv1[kt] = *(const f8frag*)(wsb + 4096 + kt * 512);
      Wv2[kt] = *(const f8frag*)(wsb + 8192 + kt * 512);
      Wv3[kt] = *(const f8frag*)(wsb + 12288 + kt * 512);
    }
    PIN_A8(Wv0); PIN_A8(Wv1); PIN_A8(Wv2); PIN_A8(Wv3);
    __syncthreads();   // hbufS[0] complete; s=0 hG store drained

    for (int s = 1; s < 128; s++) {
      PIN_A8(Wv0); PIN_A8(Wv1); PIN_A8(Wv2); PIN_A8(Wv3);
      asm volatile("" : "+v"(rbv0), "+v"(rbv1), "+v"(rbv2), "+v"(rbv3));
      const u8* h8 = &hbufS[(s - 1) & 1][lane * 8];
      f32x4 ai = rbv0, af_ = rbv1, ag = rbv2, ao = rbv3;
#pragma unroll
      for (int kt = 0; kt < 8; kt++) {
        f8frag a8 = *(const f8frag*)(h8 + kt * 512);
        ai  = MFMA8(Wv0[kt], a8, ai);
        af_ = MFMA8(Wv1[kt], a8, af_);
        ag  = MFMA8(Wv2[kt], a8, ag);
        ao  = MFMA8(Wv3[kt], a8, ao);
      }
      float hn[4];
#pragma unroll
      for (int r = 0; r < 4; r++) {
        float2 hc2 = lstm2(ai[r], af_[r], ag[r], ao[r], cst[r]);
        hn[r] = hc2.x;
        cst[r] = hc2.y;
      }
      unsigned hv = pk4_e4m3(hn[0], hn[1], hn[2], hn[3]);
      *(unsigned*)(&hbufS[s & 1][wroff]) = hv;
      __hip_atomic_store((unsigned*)(hGs + (size_t)s * 4096), hv,
                         __ATOMIC_RELAXED, __HIP_MEMORY_SCOPE_AGENT);
      if ((s & 3) == 3) {   // publish chunk s>>2 (drain + release)
        __syncthreads();
        if (tid == 0)
          __hip_atomic_store(flags + b, (unsigned)((s >> 2) + 1),
                             __ATOMIC_RELEASE, __HIP_MEMORY_SCOPE_AGENT);
      } else {
        LDS_BARRIER();      // ping-pong only; hG acks float freely
      }
    }
  } else {
    // ================= consumer (R12 body, verbatim) =================
    const int b = blockIdx.x - 64;
    const int rowg = b * 16;
    for (int i = tid; i < 2 * 16 * 40; i += 1024) (&hp8[0][0][0])[i] = 0;
    const u8* pwsb = pWsS + (size_t)(w & 7) * 4096 + lane * 8;
    f8frag pbv[8];
#pragma unroll
    for (int kt = 0; kt < 8; kt++) pbv[kt] = *(const f8frag*)(pwsb + kt * 512);
    f8frag phw = *(const f8frag*)(pWhhS + (size_t)(w & 7) * 512 + lane * 8);
    PIN_V8(pbv);
    asm volatile("" : "+v"(phw));
    const f32x4 pbias = *(const f32x4*)(pb + (w & 7) * 16 + q * 4);
    float cp = 0.f;
    const u8* hGc = hG + (size_t)b * 524288;
    const int t_si = (tid >> 3) >> 4, t_r = (tid >> 3) & 15, sub = tid & 7;

    for (int cs = 0; cs < 32; cs++) {
      if (tid == 0) {
        while (__hip_atomic_load(flags + b, __ATOMIC_ACQUIRE,
                                 __HIP_MEMORY_SCOPE_AGENT) < (unsigned)(cs + 1))
          __builtin_amdgcn_s_sleep(2);
      }
      __syncthreads();   // chunk cs visible to all threads
      {
        const unsigned* src = (const unsigned*)(hGc + (size_t)cs * 16384) + tid * 4;
        unsigned d0 = __hip_atomic_load(src + 0, __ATOMIC_RELAXED, __HIP_MEMORY_SCOPE_AGENT);
        unsigned d1 = __hip_atomic_load(src + 1, __ATOMIC_RELAXED, __HIP_MEMORY_SCOPE_AGENT);
        unsigned d2 = __hip_atomic_load(src + 2, __ATOMIC_RELAXED, __HIP_MEMORY_SCOPE_AGENT);
        unsigned d3 = __hip_atomic_load(src + 3, __ATOMIC_RELAXED, __HIP_MEMORY_SCOPE_AGENT);
        int4 vv; vv.x = d0; vv.y = d1; vv.z = d2; vv.w = d3;
        *(int4*)&stageL[tid * 16] = vv;
      }
      __syncthreads();   // stage complete
#pragma unroll
      for (int si = 0; si < 4; si++) {
        const int s = cs * 4 + si;
        if (w < 8) {
          const u8* xr8 = &stageL[si * 4096 + lane * 8];
          f32x4 pacc = pbias;
#pragma unroll
          for (int kt = 0; kt < 8; kt++) {
            f8frag pav = *(const f8frag*)(xr8 + kt * 512);
            pacc = MFMA8(pbv[kt], pav, pacc);
          }
          f8frag pah = *(const f8frag*)(&hp8[s & 1][m15][q * 8]);
          pacc = MFMA8(phw, pah, pacc);
          // lane (m15,q): gates i,f,g,o of (batch m15, predcol w*4+q)
          float2 hc2 = lstm2(pacc[0], pacc[1], pacc[2], pacc[3], cp);
          cp = hc2.y;
          hp8[(s + 1) & 1][m15][w * 4 + q] = f2e4m3(hc2.x);
          ysC[si][m15][w * 4 + q] = hc2.x;
        }
        LDS_BARRIER();
      }
      // fused softmax + sigmoid + final store for this chunk
      if (tid < 512) {
        f32x4 yv = *(const f32x4*)&ysC[t_si][t_r][sub * 4];
        float v3 = (sub == 7) ? -1e30f : yv[3];
        float m = fmaxf(fmaxf(yv[0], yv[1]), fmaxf(yv[2], v3));
#pragma unroll
        for (int off = 4; off; off >>= 1) m = fmaxf(m, __shfl_xor(m, off, 8));
        float e0 = __expf(yv[0] - m), e1 = __expf(yv[1] - m), e2 = __expf(yv[2] - m);
        float e3 = (sub == 7) ? 0.f : __expf(yv[3] - m);
        float tot = e0 + e1 + e2 + e3;
#pragma unroll
        for (int off = 4; off; off >>= 1) tot += __shfl_xor(tot, off, 8);
        float inv = rcp(tot);
        f32x4 o;
        o[0] = e0 * inv; o[1] = e1 * inv; o[2] = e2 * inv;
        o[3] = (sub == 7) ? ssig(yv[3]) : e3 * inv;
        *(f32x4*)(out + (size_t)(rowg + t_r) * 4096 + (cs * 4 + t_si) * 32 + sub * 4) = o;
      }
      LDS_BARRIER();   // ysC/stage consumed before next chunk overwrites
    }
  }
}

// ---------------------------------------------------------------------------
extern "C" void kernel_launch(void* const* d_in, const int* in_sizes, int n_in,
                              void* d_out, int out_size, void* d_ws, size_t ws_size,
                              hipStream_t stream) {
  (void)in_sizes; (void)n_in; (void)out_size; (void)ws_size;
  const float* x    = (const float*)d_in[0];
  const float* W1   = (const float*)d_in[1];
  const float* b1   = (const float*)d_in[2];
  const float* W2   = (const float*)d_in[3];
  const float* b2   = (const float*)d_in[4];
  const float* W3   = (const float*)d_in[5];
  const float* b3   = (const float*)d_in[6];
  const float* Wh1  = (const float*)d_in[7];
  const float* bh1  = (const float*)d_in[8];
  const float* Wh2  = (const float*)d_in[9];
  const float* bh2  = (const float*)d_in[10];
  const float* Wc1  = (const float*)d_in[11];
  const float* bc1  = (const float*)d_in[12];
  const float* Wc2  = (const float*)d_in[13];
  const float* bc2  = (const float*)d_in[14];
  const float* Wx1  = (const float*)d_in[15];
  const float* bx1  = (const float*)d_in[16];
  const float* Wx2  = (const float*)d_in[17];
  const float* bx2  = (const float*)d_in[18];
  const float* rWih = (const float*)d_in[19];
  const float* rWhh = (const float*)d_in[20];
  const float* rbih = (const float*)d_in[21];
  const float* rbhh = (const float*)d_in[22];
  const float* pWih = (const float*)d_in[23];
  const float* pWhh = (const float*)d_in[24];
  const float* pbih = (const float*)d_in[25];
  const float* pbhh = (const float*)d_in[26];

  char* w = (char*)d_ws;
  auto alloc = [&](size_t bytes) -> char* {
    char* p = w;
    w += (bytes + 255) & ~(size_t)255;
    return p;
  };
  u16* Xbf  = (u16*)alloc(1024 * 128 * 2);
  u16* T1   = (u16*)alloc(1024 * 512 * 2);
  u16* T2   = (u16*)alloc(1024 * 512 * 2);
  u16* T3   = (u16*)alloc(1024 * 512 * 2);
  u16* TH   = (u16*)alloc(1024 * 512 * 2);
  u16* TC   = (u16*)alloc(1024 * 512 * 2);
  u16* TX   = (u16*)alloc(1024 * 512 * 2);
  u16* X0H  = (u16*)alloc(1024 * 512 * 2);  // cols 0..255 = x0, 256..511 = h
  float* CB = (float*)alloc(1024 * 256 * 4);
  u16* W1b  = (u16*)alloc(512 * 128 * 2);
  u16* W2b  = (u16*)alloc(512 * 512 * 2);
  u16* W3b  = (u16*)alloc(512 * 512 * 2);
  u16* Wh1b = (u16*)alloc(512 * 512 * 2);
  u16* Wc1b = (u16*)alloc(512 * 512 * 2);
  u16* Wx1b = (u16*)alloc(512 * 512 * 2);
  u16* Wh2b = (u16*)alloc(256 * 512 * 2);
  u16* Wc2b = (u16*)alloc(256 * 512 * 2);
  u16* Wx2b = (u16*)alloc(256 * 512 * 2);
  u16* WcatR= (u16*)alloc(1024 * 512 * 2);
  u8*  WsS  = (u8*)alloc(262144);
  u8*  pWsS = (u8*)alloc(32768);
  u8*  pWhhS= (u8*)alloc(4096);
  float* rbR = (float*)alloc(1024 * 4);
  float* pbR = (float*)alloc(128 * 4);
  unsigned* flags = (unsigned*)alloc(64 * 4);
  u8*  hG   = (u8*)alloc((size_t)64 * 128 * 4096);   // 32 MB fp8 h stream

  PrepArgs pa;
  pa.x = x; pa.W1 = W1; pa.W2 = W2; pa.W3 = W3; pa.Wh1 = Wh1; pa.Wc1 = Wc1; pa.Wx1 = Wx1;
  pa.Wh2 = Wh2; pa.Wc2 = Wc2; pa.Wx2 = Wx2;
  pa.rWih = rWih; pa.rWhh = rWhh; pa.rbih = rbih; pa.rbhh = rbhh;
  pa.pWih = pWih; pa.pWhh = pWhh; pa.pbih = pbih; pa.pbhh = pbhh;
  pa.Xbf = Xbf; pa.W1b = W1b; pa.W2b = W2b; pa.W3b = W3b; pa.Wh1b = Wh1b;
  pa.Wc1b = Wc1b; pa.Wx1b = Wx1b; pa.Wh2b = Wh2b; pa.Wc2b = Wc2b; pa.Wx2b = Wx2b;
  pa.WcatR = WcatR;
  pa.WsS = WsS; pa.pWsS = pWsS; pa.pWhhS = pWhhS;
  pa.rbR = rbR; pa.pbR = pbR;
  pa.flags = flags;
  prep<<<dim3(32, 16), 256, 0, stream>>>(pa);

  // MLP trunk
  gemm_act<<<dim3(16, 8), 256, 0, stream>>>(Xbf, W1b, b1, T1, nullptr, 128, 512, 0, 1);
  gemm_act<<<dim3(16, 8), 256, 0, stream>>>(T1, W2b, b2, T2, nullptr, 512, 512, 0, 1);
  gemm_act<<<dim3(16, 8), 256, 0, stream>>>(T2, W3b, b3, T3, nullptr, 512, 512, 0, 1);
  // heads layer 1 (3 gemms, one dispatch)
  G3 h1a = {T3, Wh1b, bh1, TH, nullptr, 512, 512, 0, 1};
  G3 h1b = {T3, Wc1b, bc1, TC, nullptr, 512, 512, 0, 1};
  G3 h1c = {T3, Wx1b, bx1, TX, nullptr, 512, 512, 0, 1};
  gemm_act3<<<dim3(16, 8, 3), 256, 0, stream>>>(h1a, h1b, h1c);
  // heads layer 2 (3 gemms, one dispatch)
  G3 h2a = {TH, Wh2b, bh2, X0H, nullptr, 512, 512, 256, 0};  // h -> X0H hi
  G3 h2b = {TC, Wc2b, bc2, nullptr, CB, 512, 256, 0, 0};     // c0 (fp32)
  G3 h2c = {TX, Wx2b, bx2, X0H, nullptr, 512, 512, 0, 0};    // x0 -> X0H lo
  gemm_act3<<<dim3(16, 4, 3), 256, 0, stream>>>(h2a, h2b, h2c);

  // fused decode (step0 prologue + 127 steps) || pred (+fused softmax)
  decode_pred<<<128, 1024, 0, stream>>>(WsS, WcatR, rbR, CB, X0H,
                                        pWsS, pWhhS, pbR,
                                        (float*)d_out, hG, flags);
}

// Round 16
// 458.723 us; speedup vs baseline: 1.8580x; 1.8580x over previous
//
#include <hip/hip_runtime.h>
#include <hip/hip_fp8.h>

typedef unsigned short u16;
typedef unsigned char u8;
typedef __attribute__((ext_vector_type(8))) __bf16 bfrag;
typedef long long f8frag;
typedef __attribute__((ext_vector_type(4))) float f32x4;

static __device__ __forceinline__ f32x4 MFMA(bfrag a, bfrag b, f32x4 c) {
  return __builtin_amdgcn_mfma_f32_16x16x32_bf16(a, b, c, 0, 0, 0);
}
static __device__ __forceinline__ f32x4 MFMA8(f8frag a, f8frag b, f32x4 c) {
  return __builtin_amdgcn_mfma_f32_16x16x32_fp8_fp8(a, b, c, 0, 0, 0);
}

// float -> bf16 (RNE)
static __device__ __forceinline__ u16 f2b(float f) {
  union { float f; unsigned u; } v; v.f = f;
  unsigned r = (v.u + 0x7fffu + ((v.u >> 16) & 1u)) >> 16;
  return (u16)r;
}
// float -> fp8 e4m3 via HW cvt (gfx950: OCP e4m3fn)
static __device__ __forceinline__ u8 f2e4m3(float f) {
  return (u8)(__builtin_amdgcn_cvt_pk_fp8_f32(f, f, 0, false) & 0xff);
}
static __device__ __forceinline__ unsigned pk4_e4m3(float a, float b, float c, float d) {
  int p = __builtin_amdgcn_cvt_pk_fp8_f32(a, b, 0, false);
  p = __builtin_amdgcn_cvt_pk_fp8_f32(c, d, p, true);
  return (unsigned)p;
}
// 1.f/x without fast-math emits the IEEE div sequence (~8 ops); v_rcp is 1.
static __device__ __forceinline__ float rcp(float x) { return __builtin_amdgcn_rcpf(x); }
static __device__ __forceinline__ float ssig(float x) {
  float E = __expf(x);
  return E * rcp(1.f + E);
}
// Shared-denominator LSTM cell (harness-verified R6/R9/R10/R12):
// cn = [c*Ef*QR + Ei*P*(Eg-1)] / (P*QR), hn = Eo(Ec-1)/[(1+Eo)(Ec+1)].
static __device__ __forceinline__ float2 lstm2(float gi, float gf, float gg,
                                               float go, float c) {
  float Ei = __expf(gi), Ef = __expf(gf), Eg = __expf(2.f * gg), Eo = __expf(go);
  float P = 1.f + Ef, Q = 1.f + Ei, R = 1.f + Eg;
  float QR = Q * R;
  float num = c * Ef * QR + Ei * P * (Eg - 1.f);
  float cn = num * rcp(P * QR);
  float Ec = __expf(2.f * cn);
  float hn = Eo * (Ec - 1.f) * rcp((1.f + Eo) * (Ec + 1.f));
  return make_float2(hn, cn);
}

// barrier that waits only on LDS traffic (no vmcnt store-ack drain)
#define LDS_BARRIER() asm volatile("s_waitcnt lgkmcnt(0)\ns_barrier" ::: "memory")
#define PIN_A8(A) asm volatile("" : "+a"(A[0]), "+a"(A[1]), "+a"(A[2]), "+a"(A[3]), \
                                    "+a"(A[4]), "+a"(A[5]), "+a"(A[6]), "+a"(A[7]))
#define PIN_V8(A) asm volatile("" : "+v"(A[0]), "+v"(A[1]), "+v"(A[2]), "+v"(A[3]), \
                                    "+v"(A[4]), "+v"(A[5]), "+v"(A[6]), "+v"(A[7]))

// ---------------------------------------------------------------------------
// prep (R10/R12 layouts, harness-verified; case 14 zeroes the flags)
// ---------------------------------------------------------------------------
struct PrepArgs {
  const float *x, *W1, *W2, *W3, *Wh1, *Wc1, *Wx1, *Wh2, *Wc2, *Wx2;
  const float *rWih, *rWhh, *rbih, *rbhh, *pWih, *pWhh, *pbih, *pbhh;
  u16 *Xbf, *W1b, *W2b, *W3b, *Wh1b, *Wc1b, *Wx1b, *Wh2b, *Wc2b, *Wx2b;
  u16 *WcatR;
  u8 *WsS, *pWsS, *pWhhS;
  float *rbR, *pbR;
  unsigned *flags;
};

static __device__ __forceinline__ void emit_stream(u16* dst, const float* src,
                                                   int i, int K, int ktbits) {
  int j = i & 7, lane = (i >> 3) & 63;
  int kt = (i >> 9) & ((1 << ktbits) - 1);
  int nt = (i >> (9 + ktbits)) & 3;
  int ct = i >> (11 + ktbits);
  int srow = ct * 64 + nt * 16 + (lane & 15);
  int scol = kt * 32 + ((lane >> 4) & 3) * 8 + j;
  dst[i] = f2b(src[srow * K + scol]);
}

__global__ __launch_bounds__(256) void prep(PrepArgs p) {
  const int tid0 = blockIdx.x * 256 + threadIdx.x;
  const int stride = gridDim.x * 256;
  switch (blockIdx.y) {
    case 0: for (int i = tid0; i < 131072; i += stride) p.Xbf[i] = f2b(p.x[i]); break;
    case 1: for (int i = tid0; i < 65536;  i += stride) emit_stream(p.W1b, p.W1, i, 128, 2); break;
    case 2: for (int i = tid0; i < 262144; i += stride) emit_stream(p.W2b, p.W2, i, 512, 4); break;
    case 3: for (int i = tid0; i < 262144; i += stride) emit_stream(p.W3b, p.W3, i, 512, 4); break;
    case 4: for (int i = tid0; i < 262144; i += stride) emit_stream(p.Wh1b, p.Wh1, i, 512, 4); break;
    case 5: for (int i = tid0; i < 262144; i += stride) emit_stream(p.Wc1b, p.Wc1, i, 512, 4); break;
    case 6: for (int i = tid0; i < 262144; i += stride) emit_stream(p.Wx1b, p.Wx1, i, 512, 4); break;
    case 7: for (int i = tid0; i < 131072; i += stride) emit_stream(p.Wh2b, p.Wh2, i, 512, 4); break;
    case 8: for (int i = tid0; i < 131072; i += stride) emit_stream(p.Wc2b, p.Wc2, i, 512, 4); break;
    case 9: for (int i = tid0; i < 131072; i += stride) emit_stream(p.Wx2b, p.Wx2, i, 512, 4); break;
    case 10: // step-0 concat weights, gate-retiled + stream (K=512)
      for (int i = tid0; i < 524288; i += stride) {
        int j = i & 7, lane = (i >> 3) & 63, kt = (i >> 9) & 15;
        int gate = (i >> 13) & 3, w16 = i >> 15;
        int srow = gate * 256 + w16 * 16 + (lane & 15);
        int k = kt * 32 + ((lane >> 4) & 3) * 8 + j;
        float v = (k < 256) ? p.rWih[srow * 256 + k] : p.rWhh[srow * 256 + (k - 256)];
        p.WcatR[i] = f2b(v);
      }
      break;
    case 11:
      for (int i = tid0; i < 1024; i += stride) {
        int srow = (((i >> 4) & 3) << 8) + ((i >> 6) << 4) + (i & 15);
        p.rbR[i] = p.rbih[srow] + p.rbhh[srow];
      }
      break;
    case 12: // pred x-weights fp8, swizzled-contiguous
      for (int i = tid0; i < 32768; i += stride) {
        int j = i & 7, lane = (i >> 3) & 63, kt = (i >> 9) & 7, w = i >> 12;
        int n = w * 16 + (lane & 15);
        int srow = ((n & 3) << 5) + (n >> 2);
        int k = kt * 32 + ((lane >> 4) & 3) * 8 + j;
        p.pWsS[i] = f2e4m3(p.pWih[srow * 256 + k]);
      }
      break;
    case 13: // pred h-weights fp8, swizzled-contiguous
      for (int i = tid0; i < 4096; i += stride) {
        int j = i & 7, lane = (i >> 3) & 63, w = i >> 9;
        int n = w * 16 + (lane & 15);
        int srow = ((n & 3) << 5) + (n >> 2);
        int k = ((lane >> 4) & 3) * 8 + j;
        p.pWhhS[i] = f2e4m3(p.pWhh[srow * 32 + k]);
      }
      break;
    case 14:
      for (int i = tid0; i < 128; i += stride) {
        int srow = ((i & 3) << 5) + (i >> 2);
        p.pbR[i] = p.pbih[srow] + p.pbhh[srow];
      }
      for (int i = tid0; i < 64; i += stride)
        __hip_atomic_store(p.flags + i, 0u, __ATOMIC_RELAXED, __HIP_MEMORY_SCOPE_AGENT);
      break;
    case 15: // decode combined weights fp8, swizzled-contiguous stream layout
      for (int i = tid0; i < 262144; i += stride) {
        int j = i & 7, lane = (i >> 3) & 63, kt = (i >> 9) & 7;
        int gate = (i >> 12) & 3, g16 = i >> 14;
        int srow = gate * 256 + g16 * 16 + (lane & 15);
        int k = kt * 32 + ((lane >> 4) & 3) * 8 + j;
        p.WsS[i] = f2e4m3(p.rWih[srow * 256 + k] + p.rWhh[srow * 256 + k]);
      }
      break;
  }
}

// ---------------------------------------------------------------------------
// gemm_act: Y[1024,N] = act(X[1024,K] @ W^T + bias), stream-layout weights.
// ---------------------------------------------------------------------------
__global__ __launch_bounds__(256) void gemm_act(
    const u16* __restrict__ X, const u16* __restrict__ W,
    const float* __restrict__ bias,
    u16* __restrict__ Yb, float* __restrict__ Yf,
    int K, int ldo, int coloff, int leaky) {
  const int rt = blockIdx.x, ct = blockIdx.y;
  const int lane = threadIdx.x & 63, wave = threadIdx.x >> 6;
  const int m15 = lane & 15, q = lane >> 4, kq = q * 8;
  const int KT = K >> 5;
  const int row = rt * 64 + wave * 16 + m15;
  f32x4 acc[4] = {};
  const u16* xp = X + (size_t)row * K + kq;
  const u16* wst = W + lane * 8;
  for (int kt = 0; kt < KT; kt++) {
    bfrag a = *(const bfrag*)(xp + kt * 32);
#pragma unroll
    for (int nt = 0; nt < 4; nt++) {
      const u16* wp = wst + (size_t)((ct * 4 + nt) * KT + kt) * 512;
      acc[nt] = MFMA(a, *(const bfrag*)wp, acc[nt]);
    }
  }
#pragma unroll
  for (int nt = 0; nt < 4; nt++) {
    int col = ct * 64 + nt * 16 + m15;
    float bv = bias[col];
#pragma unroll
    for (int r = 0; r < 4; r++) {
      int orow = rt * 64 + wave * 16 + q * 4 + r;
      float v = acc[nt][r] + bv;
      if (leaky) v = v >= 0.f ? v : 0.2f * v;
      if (Yb) Yb[(size_t)orow * ldo + coloff + col] = f2b(v);
      else    Yf[(size_t)orow * ldo + coloff + col] = v;
    }
  }
}

// three independent gemms in one dispatch (blockIdx.z selects)
struct G3 {
  const u16 *X, *W;
  const float* bias;
  u16* Yb;
  float* Yf;
  int K, ldo, coloff, leaky;
};
__global__ __launch_bounds__(256) void gemm_act3(G3 ga, G3 gb, G3 gc) {
  G3 g = (blockIdx.z == 0) ? ga : (blockIdx.z == 1) ? gb : gc;
  const int rt = blockIdx.x, ct = blockIdx.y;
  const int lane = threadIdx.x & 63, wave = threadIdx.x >> 6;
  const int m15 = lane & 15, q = lane >> 4, kq = q * 8;
  const int KT = g.K >> 5;
  const int row = rt * 64 + wave * 16 + m15;
  f32x4 acc[4] = {};
  const u16* xp = g.X + (size_t)row * g.K + kq;
  const u16* wst = g.W + lane * 8;
  for (int kt = 0; kt < KT; kt++) {
    bfrag a = *(const bfrag*)(xp + kt * 32);
#pragma unroll
    for (int nt = 0; nt < 4; nt++) {
      const u16* wp = wst + (size_t)((ct * 4 + nt) * KT + kt) * 512;
      acc[nt] = MFMA(a, *(const bfrag*)wp, acc[nt]);
    }
  }
#pragma unroll
  for (int nt = 0; nt < 4; nt++) {
    int col = ct * 64 + nt * 16 + m15;
    float bv = g.bias[col];
#pragma unroll
    for (int r = 0; r < 4; r++) {
      int orow = rt * 64 + wave * 16 + q * 4 + r;
      float v = acc[nt][r] + bv;
      if (g.leaky) v = v >= 0.f ? v : 0.2f * v;
      if (g.Yb) g.Yb[(size_t)orow * g.ldo + g.coloff + col] = f2b(v);
      else      g.Yf[(size_t)orow * g.ldo + g.coloff + col] = v;
    }
  }
}

// ---------------------------------------------------------------------------
// decode_pred v16 (R12, session best — 459.2us verified): fused
// producer/consumer. Producer (blocks 0-63) = R10's decode_h (K=512
// prologue + steady loop: gates i/f/g in 48 AGPRs, gate-o in LDS) with
// agent-scope hG stores + chunk flag (4 steps) released after a
// vmcnt-draining __syncthreads. Consumer (blocks 64-127) = pred + fused
// softmax, acquire-spin per chunk. R15 lesson: do NOT pin more (64-AGPR
// pin + 16 bias VGPRs overflows arch side -> 270MB scratch spill traffic).
// ---------------------------------------------------------------------------
__global__ __attribute__((amdgpu_flat_work_group_size(1024, 1024), amdgpu_waves_per_eu(4, 4)))
void decode_pred(
    const u8* __restrict__ WsS,     // [262144] fp8 decode weights (stream)
    const u16* __restrict__ WcatR,  // [1024][512] bf16 step-0 weights (stream)
    const float* __restrict__ rb,   // rbR [1024]
    const float* __restrict__ CB,   // [1024][256] c0 (fp32, from c-head gemm)
    const u16* __restrict__ X0H,    // [1024][512] bf16: cols 0-255 x0, 256-511 h
    const u8* __restrict__ pWsS,    // [32768] fp8 pred x-weights (stream)
    const u8* __restrict__ pWhhS,   // [4096] fp8 pred h-weights (stream)
    const float* __restrict__ pb,   // pbR [128]
    float* __restrict__ out,        // [1024][128][32]
    u8* __restrict__ hG,            // [64][128][4096] fp8 h stream
    unsigned* __restrict__ flags) { // [64] chunk progress (4 steps/chunk)
  __shared__ __align__(16) u8 hbufS[2][4096];   // producer h ping-pong
  __shared__ __align__(16) u8 WoL[16][4096];    // producer gate-o weights
  __shared__ __align__(16) u8 stageL[16384];    // consumer 4-step stage
  __shared__ __align__(16) u8 hp8[2][16][40];   // consumer pred hidden
  __shared__ float ysC[4][16][36];              // consumer y chunk
  const int tid = threadIdx.x;
  const int w = tid >> 6, lane = tid & 63;
  const int m15 = lane & 15, q = lane >> 4;

  if (blockIdx.x < 64) {
    // ================= producer (R10 decode_h body) =================
    const int b = blockIdx.x;
    const int rowg = b * 16;
    {
      int4* dst = (int4*)WoL;
      for (int i = tid; i < 4096; i += 1024) {
        int wv = i >> 8, rest = i & 255;
        dst[i] = ((const int4*)(WsS + wv * 16384 + 12288))[rest];
      }
    }
    const float* rbp = rb + w * 64 + q * 4;
    f32x4 rbv0 = *(const f32x4*)(rbp +  0);
    f32x4 rbv1 = *(const f32x4*)(rbp + 16);
    f32x4 rbv2 = *(const f32x4*)(rbp + 32);
    f32x4 rbv3 = *(const f32x4*)(rbp + 48);
    asm volatile("" : "+v"(rbv0), "+v"(rbv1), "+v"(rbv2), "+v"(rbv3));
    f32x4 cst = *(const f32x4*)(CB + (size_t)(rowg + m15) * 256 + w * 16 + q * 4);
    const int wroff = (w >> 1) * 512 + ((w & 1) * 2 + (q >> 1)) * 128 + m15 * 8 + (q & 1) * 4;
    u8* hGs = hG + (size_t)b * 524288 + wroff;

    // ---- prologue: step 0, K=512 over [x0 | h] with stream WcatR ----
    {
      f32x4 ai = rbv0, af_ = rbv1, ag = rbv2, ao = rbv3;
      const u16* xrow = X0H + (size_t)(rowg + m15) * 512 + q * 8;
      const u16* wcw = WcatR + (size_t)w * 32768 + lane * 8;
#pragma unroll
      for (int kt = 0; kt < 16; kt++) {
        bfrag a = *(const bfrag*)(xrow + kt * 32);
        ai  = MFMA(*(const bfrag*)(wcw + kt * 512), a, ai);
        af_ = MFMA(*(const bfrag*)(wcw + 8192 + kt * 512), a, af_);
        ag  = MFMA(*(const bfrag*)(wcw + 16384 + kt * 512), a, ag);
        ao  = MFMA(*(const bfrag*)(wcw + 24576 + kt * 512), a, ao);
      }
      float hn[4];
#pragma unroll
      for (int r = 0; r < 4; r++) {
        float2 hc2 = lstm2(ai[r], af_[r], ag[r], ao[r], cst[r]);
        hn[r] = hc2.x;
        cst[r] = hc2.y;
      }
      unsigned hv = pk4_e4m3(hn[0], hn[1], hn[2], hn[3]);
      *(unsigned*)(&hbufS[0][wroff]) = hv;
      __hip_atomic_store((unsigned*)hGs, hv, __ATOMIC_RELAXED, __HIP_MEMORY_SCOPE_AGENT);
    }
    const u8* wsb = WsS + (size_t)w * 16384 + lane * 8;
    f8frag Wv0[8], Wv1[8], Wv2[8];
#pragma unroll
    for (int kt = 0; kt < 8; kt++) {
      Wv0[kt] = *(const f8frag*)(wsb + kt * 512);
      Wv1[kt] = *(const f8frag*)(wsb + 4096 + kt * 512);
      Wv2[kt] = *(const f8frag*)(wsb + 8192 + kt * 512);
    }
    PIN_A8(Wv0); PIN_A8(Wv1); PIN_A8(Wv2);
    const u8* woW = &WoL[w][lane * 8];
    __syncthreads();   // WoL + hbufS[0] complete

    for (int s = 1; s < 128; s++) {
      PIN_A8(Wv0); PIN_A8(Wv1); PIN_A8(Wv2);
      asm volatile("" : "+v"(rbv0), "+v"(rbv1), "+v"(rbv2), "+v"(rbv3));
      const u8* h8 = &hbufS[(s - 1) & 1][lane * 8];
      f32x4 ai = rbv0, af_ = rbv1, ag = rbv2, ao = rbv3;
#pragma unroll
      for (int kt = 0; kt < 8; kt++) {
        f8frag a8 = *(const f8frag*)(h8 + kt * 512);
        f8frag wo = *(const f8frag*)(woW + kt * 512);
        ai  = MFMA8(Wv0[kt], a8, ai);
        af_ = MFMA8(Wv1[kt], a8, af_);
        ag  = MFMA8(Wv2[kt], a8, ag);
        ao  = MFMA8(wo, a8, ao);
      }
      float hn[4];
#pragma unroll
      for (int r = 0; r < 4; r++) {
        float2 hc2 = lstm2(ai[r], af_[r], ag[r], ao[r], cst[r]);
        hn[r] = hc2.x;
        cst[r] = hc2.y;
      }
      unsigned hv = pk4_e4m3(hn[0], hn[1], hn[2], hn[3]);
      *(unsigned*)(&hbufS[s & 1][wroff]) = hv;
      __hip_atomic_store((unsigned*)(hGs + (size_t)s * 4096), hv,
                         __ATOMIC_RELAXED, __HIP_MEMORY_SCOPE_AGENT);
      if ((s & 3) == 3) {   // publish chunk s>>2 (drain + release)
        __syncthreads();
        if (tid == 0)
          __hip_atomic_store(flags + b, (unsigned)((s >> 2) + 1),
                             __ATOMIC_RELEASE, __HIP_MEMORY_SCOPE_AGENT);
      } else {
        LDS_BARRIER();      // ping-pong only; hG acks float freely
      }
    }
  } else {
    // ================= consumer (pred + fused softmax + spin) ============
    const int b = blockIdx.x - 64;
    const int rowg = b * 16;
    for (int i = tid; i < 2 * 16 * 40; i += 1024) (&hp8[0][0][0])[i] = 0;
    const u8* pwsb = pWsS + (size_t)(w & 7) * 4096 + lane * 8;
    f8frag pbv[8];
#pragma unroll
    for (int kt = 0; kt < 8; kt++) pbv[kt] = *(const f8frag*)(pwsb + kt * 512);
    f8frag phw = *(const f8frag*)(pWhhS + (size_t)(w & 7) * 512 + lane * 8);
    PIN_V8(pbv);
    asm volatile("" : "+v"(phw));
    const f32x4 pbias = *(const f32x4*)(pb + (w & 7) * 16 + q * 4);
    float cp = 0.f;
    const u8* hGc = hG + (size_t)b * 524288;
    const int t_si = (tid >> 3) >> 4, t_r = (tid >> 3) & 15, sub = tid & 7;

    for (int cs = 0; cs < 32; cs++) {
      if (tid == 0) {
        while (__hip_atomic_load(flags + b, __ATOMIC_ACQUIRE,
                                 __HIP_MEMORY_SCOPE_AGENT) < (unsigned)(cs + 1))
          __builtin_amdgcn_s_sleep(2);
      }
      __syncthreads();   // chunk cs visible to all threads
      {
        const unsigned* src = (const unsigned*)(hGc + (size_t)cs * 16384) + tid * 4;
        unsigned d0 = __hip_atomic_load(src + 0, __ATOMIC_RELAXED, __HIP_MEMORY_SCOPE_AGENT);
        unsigned d1 = __hip_atomic_load(src + 1, __ATOMIC_RELAXED, __HIP_MEMORY_SCOPE_AGENT);
        unsigned d2 = __hip_atomic_load(src + 2, __ATOMIC_RELAXED, __HIP_MEMORY_SCOPE_AGENT);
        unsigned d3 = __hip_atomic_load(src + 3, __ATOMIC_RELAXED, __HIP_MEMORY_SCOPE_AGENT);
        int4 vv; vv.x = d0; vv.y = d1; vv.z = d2; vv.w = d3;
        *(int4*)&stageL[tid * 16] = vv;
      }
      __syncthreads();   // stage complete
#pragma unroll
      for (int si = 0; si < 4; si++) {
        const int s = cs * 4 + si;
        if (w < 8) {
          const u8* xr8 = &stageL[si * 4096 + lane * 8];
          f32x4 pacc = pbias;
#pragma unroll
          for (int kt = 0; kt < 8; kt++) {
            f8frag pav = *(const f8frag*)(xr8 + kt * 512);
            pacc = MFMA8(pbv[kt], pav, pacc);
          }
          f8frag pah = *(const f8frag*)(&hp8[s & 1][m15][q * 8]);
          pacc = MFMA8(phw, pah, pacc);
          // lane (m15,q): gates i,f,g,o of (batch m15, predcol w*4+q)
          float2 hc2 = lstm2(pacc[0], pacc[1], pacc[2], pacc[3], cp);
          cp = hc2.y;
          hp8[(s + 1) & 1][m15][w * 4 + q] = f2e4m3(hc2.x);
          ysC[si][m15][w * 4 + q] = hc2.x;
        }
        LDS_BARRIER();
      }
      // fused softmax + sigmoid + final store for this chunk
      if (tid < 512) {
        f32x4 yv = *(const f32x4*)&ysC[t_si][t_r][sub * 4];
        float v3 = (sub == 7) ? -1e30f : yv[3];
        float m = fmaxf(fmaxf(yv[0], yv[1]), fmaxf(yv[2], v3));
#pragma unroll
        for (int off = 4; off; off >>= 1) m = fmaxf(m, __shfl_xor(m, off, 8));
        float e0 = __expf(yv[0] - m), e1 = __expf(yv[1] - m), e2 = __expf(yv[2] - m);
        float e3 = (sub == 7) ? 0.f : __expf(yv[3] - m);
        float tot = e0 + e1 + e2 + e3;
#pragma unroll
        for (int off = 4; off; off >>= 1) tot += __shfl_xor(tot, off, 8);
        float inv = rcp(tot);
        f32x4 o;
        o[0] = e0 * inv; o[1] = e1 * inv; o[2] = e2 * inv;
        o[3] = (sub == 7) ? ssig(yv[3]) : e3 * inv;
        *(f32x4*)(out + (size_t)(rowg + t_r) * 4096 + (cs * 4 + t_si) * 32 + sub * 4) = o;
      }
      LDS_BARRIER();   // ysC/stage consumed before next chunk overwrites
    }
  }
}

// ---------------------------------------------------------------------------
extern "C" void kernel_launch(void* const* d_in, const int* in_sizes, int n_in,
                              void* d_out, int out_size, void* d_ws, size_t ws_size,
                              hipStream_t stream) {
  (void)in_sizes; (void)n_in; (void)out_size; (void)ws_size;
  const float* x    = (const float*)d_in[0];
  const float* W1   = (const float*)d_in[1];
  const float* b1   = (const float*)d_in[2];
  const float* W2   = (const float*)d_in[3];
  const float* b2   = (const float*)d_in[4];
  const float* W3   = (const float*)d_in[5];
  const float* b3   = (const float*)d_in[6];
  const float* Wh1  = (const float*)d_in[7];
  const float* bh1  = (const float*)d_in[8];
  const float* Wh2  = (const float*)d_in[9];
  const float* bh2  = (const float*)d_in[10];
  const float* Wc1  = (const float*)d_in[11];
  const float* bc1  = (const float*)d_in[12];
  const float* Wc2  = (const float*)d_in[13];
  const float* bc2  = (const float*)d_in[14];
  const float* Wx1  = (const float*)d_in[15];
  const float* bx1  = (const float*)d_in[16];
  const float* Wx2  = (const float*)d_in[17];
  const float* bx2  = (const float*)d_in[18];
  const float* rWih = (const float*)d_in[19];
  const float* rWhh = (const float*)d_in[20];
  const float* rbih = (const float*)d_in[21];
  const float* rbhh = (const float*)d_in[22];
  const float* pWih = (const float*)d_in[23];
  const float* pWhh = (const float*)d_in[24];
  const float* pbih = (const float*)d_in[25];
  const float* pbhh = (const float*)d_in[26];

  char* w = (char*)d_ws;
  auto alloc = [&](size_t bytes) -> char* {
    char* p = w;
    w += (bytes + 255) & ~(size_t)255;
    return p;
  };
  u16* Xbf  = (u16*)alloc(1024 * 128 * 2);
  u16* T1   = (u16*)alloc(1024 * 512 * 2);
  u16* T2   = (u16*)alloc(1024 * 512 * 2);
  u16* T3   = (u16*)alloc(1024 * 512 * 2);
  u16* TH   = (u16*)alloc(1024 * 512 * 2);
  u16* TC   = (u16*)alloc(1024 * 512 * 2);
  u16* TX   = (u16*)alloc(1024 * 512 * 2);
  u16* X0H  = (u16*)alloc(1024 * 512 * 2);  // cols 0..255 = x0, 256..511 = h
  float* CB = (float*)alloc(1024 * 256 * 4);
  u16* W1b  = (u16*)alloc(512 * 128 * 2);
  u16* W2b  = (u16*)alloc(512 * 512 * 2);
  u16* W3b  = (u16*)alloc(512 * 512 * 2);
  u16* Wh1b = (u16*)alloc(512 * 512 * 2);
  u16* Wc1b = (u16*)alloc(512 * 512 * 2);
  u16* Wx1b = (u16*)alloc(512 * 512 * 2);
  u16* Wh2b = (u16*)alloc(256 * 512 * 2);
  u16* Wc2b = (u16*)alloc(256 * 512 * 2);
  u16* Wx2b = (u16*)alloc(256 * 512 * 2);
  u16* WcatR= (u16*)alloc(1024 * 512 * 2);
  u8*  WsS  = (u8*)alloc(262144);
  u8*  pWsS = (u8*)alloc(32768);
  u8*  pWhhS= (u8*)alloc(4096);
  float* rbR = (float*)alloc(1024 * 4);
  float* pbR = (float*)alloc(128 * 4);
  unsigned* flags = (unsigned*)alloc(64 * 4);
  u8*  hG   = (u8*)alloc((size_t)64 * 128 * 4096);   // 32 MB fp8 h stream

  PrepArgs pa;
  pa.x = x; pa.W1 = W1; pa.W2 = W2; pa.W3 = W3; pa.Wh1 = Wh1; pa.Wc1 = Wc1; pa.Wx1 = Wx1;
  pa.Wh2 = Wh2; pa.Wc2 = Wc2; pa.Wx2 = Wx2;
  pa.rWih = rWih; pa.rWhh = rWhh; pa.rbih = rbih; pa.rbhh = rbhh;
  pa.pWih = pWih; pa.pWhh = pWhh; pa.pbih = pbih; pa.pbhh = pbhh;
  pa.Xbf = Xbf; pa.W1b = W1b; pa.W2b = W2b; pa.W3b = W3b; pa.Wh1b = Wh1b;
  pa.Wc1b = Wc1b; pa.Wx1b = Wx1b; pa.Wh2b = Wh2b; pa.Wc2b = Wc2b; pa.Wx2b = Wx2b;
  pa.WcatR = WcatR;
  pa.WsS = WsS; pa.pWsS = pWsS; pa.pWhhS = pWhhS;
  pa.rbR = rbR; pa.pbR = pbR;
  pa.flags = flags;
  prep<<<dim3(32, 16), 256, 0, stream>>>(pa);

  // MLP trunk
  gemm_act<<<dim3(16, 8), 256, 0, stream>>>(Xbf, W1b, b1, T1, nullptr, 128, 512, 0, 1);
  gemm_act<<<dim3(16, 8), 256, 0, stream>>>(T1, W2b, b2, T2, nullptr, 512, 512, 0, 1);
  gemm_act<<<dim3(16, 8), 256, 0, stream>>>(T2, W3b, b3, T3, nullptr, 512, 512, 0, 1);
  // heads layer 1 (3 gemms, one dispatch)
  G3 h1a = {T3, Wh1b, bh1, TH, nullptr, 512, 512, 0, 1};
  G3 h1b = {T3, Wc1b, bc1, TC, nullptr, 512, 512, 0, 1};
  G3 h1c = {T3, Wx1b, bx1, TX, nullptr, 512, 512, 0, 1};
  gemm_act3<<<dim3(16, 8, 3), 256, 0, stream>>>(h1a, h1b, h1c);
  // heads layer 2 (3 gemms, one dispatch)
  G3 h2a = {TH, Wh2b, bh2, X0H, nullptr, 512, 512, 256, 0};  // h -> X0H hi
  G3 h2b = {TC, Wc2b, bc2, nullptr, CB, 512, 256, 0, 0};     // c0 (fp32)
  G3 h2c = {TX, Wx2b, bx2, X0H, nullptr, 512, 512, 0, 0};    // x0 -> X0H lo
  gemm_act3<<<dim3(16, 4, 3), 256, 0, stream>>>(h2a, h2b, h2c);

  // fused decode (step0 prologue + 127 steps) || pred (+fused softmax)
  decode_pred<<<128, 1024, 0, stream>>>(WsS, WcatR, rbR, CB, X0H,
                                        pWsS, pWhhS, pbR,
                                        (float*)d_out, hG, flags);
}